// Round 3
// baseline (319.767 us; speedup 1.0000x reference)
//
#include <hip/hip_runtime.h>
#include <hip/hip_bf16.h>
#include <math.h>

#define T_TOKENS 16384
#define HDIM     2048
#define NEXP     128
#define TOPK     8

#define BM 64            // tokens per block
#define BK 64            // k-chunk (2 MFMA k-steps)
#define KPAD 72          // LDS row stride in f16 (144 B): 16B-aligned, min-bank-cycle reads

#define F16_MIN_NORM   6.1035156e-05f
#define SPLIT_SCALE    4096.0f
#define INV_SPLIT_SCALE 2.44140625e-04f   // 2^-12

typedef __attribute__((ext_vector_type(8))) _Float16 f16x8;  // 8 f16 = 4 VGPR (A/B frag)
typedef __attribute__((ext_vector_type(4))) float    f32x4;  // C/D frag

// x = hi + lo*2^-12 with hi,lo fp16 RNE; residual <= 2^-24|x|.
// Guard: never emit a subnormal-nonzero hi (MFMA denorm semantics then irrelevant).
__device__ __forceinline__ void f16split(float f, unsigned short& hi, unsigned short& lo) {
    _Float16 h = (_Float16)f;               // v_cvt_f16_f32, RNE
    float back = (float)h;
    if (fabsf(f) < F16_MIN_NORM) { h = (_Float16)0.f; back = 0.f; }
    float d = (f - back) * SPLIT_SCALE;     // f-back exact (Sterbenz); *2^12 exact
    _Float16 l = (_Float16)d;
    union { _Float16 x; unsigned short u; } ch, cl;
    ch.x = h; cl.x = l;
    hi = ch.u; lo = cl.u;
}

// ---------------- prep: split w fp32 -> w1 (f16), w2 (f16, scaled by 2^12) ----------------
__global__ __launch_bounds__(256) void split_w(const float* __restrict__ w,
                                               unsigned short* __restrict__ w1,
                                               unsigned short* __restrict__ w2) {
    int i = blockIdx.x * 256 + threadIdx.x;          // 0 .. 128*2048-1
    unsigned short h, l;
    f16split(w[i], h, l);
    w1[i] = h; w2[i] = l;
}

// ---------------- fused: logits via dual-split f16 MFMA + top-8 + renorm softmax ----------------
// 256 thr = 4 waves; tile 64 tokens x 128 experts. Wave wv: tokens [wv*16,+16) x all 128 experts.
__global__ __launch_bounds__(256) void moe_gate(const float* __restrict__ x,
                                                const unsigned short* __restrict__ w1,
                                                const unsigned short* __restrict__ w2,
                                                float* __restrict__ out_idx,
                                                float* __restrict__ out_w) {
    // x1/x2 [64][KPAD] f16 (9216 B each), w1s/w2s [128][KPAD] f16 (18432 B each) = 55296 B
    __shared__ __align__(16) unsigned char smem[55296];
    unsigned short* x1_s = (unsigned short*)smem;
    unsigned short* x2_s = (unsigned short*)(smem + 9216);
    unsigned short* w1s  = (unsigned short*)(smem + 18432);
    unsigned short* w2s  = (unsigned short*)(smem + 36864);
    float* epil = (float*)smem;                       // epilogue union: 4 x [16][132] f32 = 33792 B

    const int tid  = threadIdx.x;
    const int lane = tid & 63;
    const int wv   = tid >> 6;
    const int col  = lane & 15;       // A: m-select, B: n-select, D: col
    const int quad = lane >> 4;       // A/B: k-select, D: row group
    const long token0 = (long)blockIdx.x * BM;
    const float* xg = x + token0 * HDIM;

    f32x4 acc[8], accc[8];            // main (x1w1) and cross ((x1w2+x2w1), scale 2^-12)
#pragma unroll
    for (int n = 0; n < 8; ++n) { acc[n] = (f32x4){0,0,0,0}; accc[n] = (f32x4){0,0,0,0}; }

    float4 xv[4];                     // register prefetch buffers
    uint4  whv[4], wlv[4];

    auto load_regs = [&](int k0) {
#pragma unroll
        for (int it = 0; it < 4; ++it) {              // x tile 64x64 f32: coalesced float4
            int f = tid + it * 256;
            xv[it] = *(const float4*)(xg + (long)(f >> 4) * HDIM + k0 + (f & 15) * 4);
        }
#pragma unroll
        for (int it = 0; it < 4; ++it) {              // w tiles 128x64 f16 x2: coalesced 16B, L2-hot
            int f = tid + it * 256;
            long off = (long)(f >> 3) * HDIM + k0 + (f & 7) * 8;
            whv[it] = *(const uint4*)(w1 + off);
            wlv[it] = *(const uint4*)(w2 + off);
        }
    };

    auto store_lds = [&]() {
#pragma unroll
        for (int it = 0; it < 4; ++it) {
            int f = tid + it * 256;
            int tr = f >> 4, tc = f & 15;
            float4 v = xv[it];
            unsigned short h0, l0, h1, l1, h2, l2, h3, l3;
            f16split(v.x, h0, l0); f16split(v.y, h1, l1);
            f16split(v.z, h2, l2); f16split(v.w, h3, l3);
            uint2 hi, lo;
            hi.x = (unsigned)h0 | ((unsigned)h1 << 16);
            hi.y = (unsigned)h2 | ((unsigned)h3 << 16);
            lo.x = (unsigned)l0 | ((unsigned)l1 << 16);
            lo.y = (unsigned)l2 | ((unsigned)l3 << 16);
            *(uint2*)(x1_s + tr * KPAD + tc * 4) = hi;
            *(uint2*)(x2_s + tr * KPAD + tc * 4) = lo;
        }
#pragma unroll
        for (int it = 0; it < 4; ++it) {
            int f = tid + it * 256;
            int r = f >> 3, c = f & 7;
            *(uint4*)(w1s + r * KPAD + c * 8) = whv[it];
            *(uint4*)(w2s + r * KPAD + c * 8) = wlv[it];
        }
    };

    load_regs(0);
    for (int ch = 0; ch < HDIM / BK; ++ch) {
        store_lds();
        __syncthreads();
        if (ch < HDIM / BK - 1) load_regs((ch + 1) * BK);   // prefetch next chunk over MFMA

#pragma unroll
        for (int ks = 0; ks < 2; ++ks) {
            const int kb = ks * 32 + quad * 8;
            f16x8 a1 = *(const f16x8*)(x1_s + (wv * 16 + col) * KPAD + kb);
            f16x8 a2 = *(const f16x8*)(x2_s + (wv * 16 + col) * KPAD + kb);
#pragma unroll
            for (int nt = 0; nt < 8; ++nt) {
                f16x8 b1 = *(const f16x8*)(w1s + (nt * 16 + col) * KPAD + kb);
                f16x8 b2 = *(const f16x8*)(w2s + (nt * 16 + col) * KPAD + kb);
                acc[nt]  = __builtin_amdgcn_mfma_f32_16x16x32_f16(a1, b1, acc[nt],  0, 0, 0);
                accc[nt] = __builtin_amdgcn_mfma_f32_16x16x32_f16(a1, b2, accc[nt], 0, 0, 0);
                accc[nt] = __builtin_amdgcn_mfma_f32_16x16x32_f16(a2, b1, accc[nt], 0, 0, 0);
            }
        }
        __syncthreads();
    }

    // ---- epilogue: logit = main + cross*2^-12; D layout: token=quad*4+r, expert=nt*16+col ----
    float* my = epil + wv * (16 * 132);
#pragma unroll
    for (int nt = 0; nt < 8; ++nt)
#pragma unroll
        for (int r = 0; r < 4; ++r)
            my[(quad * 4 + r) * 132 + nt * 16 + col] = acc[nt][r] + accc[nt][r] * INV_SPLIT_SCALE;
    __syncthreads();

    for (int t = 0; t < 16; ++t) {
        float2 v = *(const float2*)(my + t * 132 + lane * 2);
        float v0 = v.x, v1 = v.y;
        const int i0 = 2 * lane, i1 = 2 * lane + 1;

        float topv[TOPK];
        int topi[TOPK];
#pragma unroll
        for (int s = 0; s < TOPK; ++s) {
            float mv = (v0 >= v1) ? v0 : v1;          // tie -> smaller index
            int   mi = (v0 >= v1) ? i0 : i1;
#pragma unroll
            for (int off = 32; off >= 1; off >>= 1) { // wave butterfly argmax
                float ov = __shfl_xor(mv, off);
                int   oi = __shfl_xor(mi, off);
                if (ov > mv || (ov == mv && oi < mi)) { mv = ov; mi = oi; }
            }
            topv[s] = mv; topi[s] = mi;
            if (i0 == mi) v0 = -INFINITY;
            if (i1 == mi) v1 = -INFINITY;
        }

        const float m = topv[0];
        float sum = 0.f;
#pragma unroll
        for (int s = 0; s < TOPK; ++s) sum += expf(topv[s] - m);
        const float inv = 1.f / sum;

        float myv = topv[0]; int myi = topi[0];
#pragma unroll
        for (int s = 1; s < TOPK; ++s)
            if (lane == s) { myv = topv[s]; myi = topi[s]; }

        if (lane < TOPK) {
            long tok = token0 + wv * 16 + t;
            out_idx[tok * TOPK + lane] = (float)myi;
            out_w[tok * TOPK + lane]   = expf(myv - m) * inv;
        }
    }
}

extern "C" void kernel_launch(void* const* d_in, const int* in_sizes, int n_in,
                              void* d_out, int out_size, void* d_ws, size_t ws_size,
                              hipStream_t stream) {
    const float* x = (const float*)d_in[0];   // [4,4096,2048] fp32
    const float* w = (const float*)d_in[1];   // [128,2048] fp32 (K-major = B^T layout already)
    float* out = (float*)d_out;               // [T*8 idx][T*8 weights] flat fp32

    unsigned short* w1 = (unsigned short*)d_ws;            // 512 KB
    unsigned short* w2 = w1 + (size_t)NEXP * HDIM;         // 512 KB

    split_w<<<(NEXP * HDIM) / 256, 256, 0, stream>>>(w, w1, w2);
    moe_gate<<<T_TOKENS / BM, 256, 0, stream>>>(x, w1, w2, out, out + (size_t)T_TOKENS * TOPK);
}

// Round 4
// 280.411 us; speedup vs baseline: 1.1404x; 1.1404x over previous
//
#include <hip/hip_runtime.h>
#include <math.h>

#define T_TOKENS 16384
#define HDIM     2048
#define NEXP     128
#define TOPK     8

#define KSPLIT   4
#define KRANGE   (HDIM / KSPLIT)     // 512 per wave
#define BKC      32                  // one 16x16x32 MFMA k-step per chunk
#define NCHUNK   (KRANGE / BKC)      // 16

#define F16_MIN_NORM    6.1035156e-05f
#define SPLIT_SCALE     4096.0f
#define INV_SPLIT_SCALE 2.44140625e-04f   // 2^-12

typedef __attribute__((ext_vector_type(8))) _Float16 f16x8;  // A/B frag: 8 f16 = 4 VGPR
typedef __attribute__((ext_vector_type(4))) float    f32x4;  // C/D frag

// x = hi + lo*2^-12 (both f16 RNE); residual <= 2^-24|x|. Verified numerics (round 3 PASS).
__device__ __forceinline__ void f16split(float f, _Float16& hi, _Float16& lo) {
    _Float16 h = (_Float16)f;
    float back = (float)h;
    if (fabsf(f) < F16_MIN_NORM) { h = (_Float16)0.f; back = 0.f; }
    lo = (_Float16)((f - back) * SPLIT_SCALE);
    hi = h;
}

// ---------------- prep: split w fp32 -> w1 (f16), w2 (f16 scaled 2^12) ----------------
__global__ __launch_bounds__(256) void split_w(const float* __restrict__ w,
                                               unsigned short* __restrict__ w1,
                                               unsigned short* __restrict__ w2) {
    int i = blockIdx.x * 256 + threadIdx.x;
    _Float16 h, l;
    f16split(w[i], h, l);
    union { _Float16 x; unsigned short u; } ch, cl;
    ch.x = h; cl.x = l;
    w1[i] = ch.u; w2[i] = cl.u;
}

// ---------------- fused gate: no-LDS K-loop, frag-direct loads, K-split x4 in block ----------------
// Block = 256 thr = 4 waves. All 4 waves: same 32 tokens x all 128 experts; wave wv owns
// K-quarter [wv*512, wv*512+512). Epilogue: LDS partial-sum + butterfly top-8 + softmax.
__global__ __launch_bounds__(256, 2) void moe_gate(const float* __restrict__ x,
                                                   const unsigned short* __restrict__ w1,
                                                   const unsigned short* __restrict__ w2,
                                                   float* __restrict__ out_idx,
                                                   float* __restrict__ out_w) {
    __shared__ float epil[KSPLIT][32][132];   // 67584 B -> 2 blocks/CU; +4 pad: 2-way max

    const int tid  = threadIdx.x;
    const int lane = tid & 63;
    const int wv   = tid >> 6;
    const int col  = lane & 15;      // A: m, B: n, D: col
    const int quad = lane >> 4;      // A/B: k-block, D: row group
    const long tok0 = (long)blockIdx.x * 32;
    const int kbase = wv * KRANGE;

    f32x4 acc[2][8], accc[2][8];     // main (x1w1) and cross ((x1w2+x2w1)*2^-12)
#pragma unroll
    for (int m = 0; m < 2; ++m)
#pragma unroll
        for (int n = 0; n < 8; ++n) { acc[m][n] = (f32x4){0,0,0,0}; accc[m][n] = (f32x4){0,0,0,0}; }

    // A: lane reads x[tok0 + mt*16 + col][kbase + ch*32 + quad*8 .. +8] (two float4).
    // Per row, the 4 quads cover 128 contiguous bytes -> good coalescing; x read exactly once.
    const float* xr0 = x + (tok0 + col) * HDIM + kbase + quad * 8;
    const float* xr1 = xr0 + 16 * HDIM;
    // B: lane reads w[nt*16 + col][same k] (one f16x8 per split). L2-resident (1 MB).
    const unsigned short* wp1 = w1 + (size_t)col * HDIM + kbase + quad * 8;
    const unsigned short* wp2 = w2 + (size_t)col * HDIM + kbase + quad * 8;

    float4 xa[4];                    // software-prefetched A (next chunk)
    xa[0] = *(const float4*)(xr0);     xa[1] = *(const float4*)(xr0 + 4);
    xa[2] = *(const float4*)(xr1);     xa[3] = *(const float4*)(xr1 + 4);

    for (int ch = 0; ch < NCHUNK; ++ch) {
        // convert current A frags
        f16x8 a1[2], a2[2];
#pragma unroll
        for (int m = 0; m < 2; ++m) {
            const float* f = (const float*)&xa[2 * m];
#pragma unroll
            for (int j = 0; j < 8; ++j) {
                _Float16 h, l;
                f16split(f[j], h, l);
                a1[m][j] = h; a2[m][j] = l;
            }
        }
        // prefetch next chunk's A (overlaps the 48 MFMAs below)
        if (ch + 1 < NCHUNK) {
            const float* p0 = xr0 + (ch + 1) * BKC;
            const float* p1 = xr1 + (ch + 1) * BKC;
            xa[0] = *(const float4*)(p0); xa[1] = *(const float4*)(p0 + 4);
            xa[2] = *(const float4*)(p1); xa[3] = *(const float4*)(p1 + 4);
        }

        const unsigned short* b1p = wp1 + ch * BKC;
        const unsigned short* b2p = wp2 + ch * BKC;
#pragma unroll
        for (int nt = 0; nt < 8; ++nt) {
            f16x8 b1 = *(const f16x8*)(b1p + (size_t)nt * 16 * HDIM);
            f16x8 b2 = *(const f16x8*)(b2p + (size_t)nt * 16 * HDIM);
            acc[0][nt]  = __builtin_amdgcn_mfma_f32_16x16x32_f16(a1[0], b1, acc[0][nt],  0, 0, 0);
            acc[1][nt]  = __builtin_amdgcn_mfma_f32_16x16x32_f16(a1[1], b1, acc[1][nt],  0, 0, 0);
            accc[0][nt] = __builtin_amdgcn_mfma_f32_16x16x32_f16(a1[0], b2, accc[0][nt], 0, 0, 0);
            accc[0][nt] = __builtin_amdgcn_mfma_f32_16x16x32_f16(a2[0], b1, accc[0][nt], 0, 0, 0);
            accc[1][nt] = __builtin_amdgcn_mfma_f32_16x16x32_f16(a1[1], b2, accc[1][nt], 0, 0, 0);
            accc[1][nt] = __builtin_amdgcn_mfma_f32_16x16x32_f16(a2[1], b1, accc[1][nt], 0, 0, 0);
        }
    }

    // ---- epilogue: per-wave K-quarter partials -> LDS ----
    // D layout (m89/m91-verified): token = mt*16 + quad*4 + r, expert = nt*16 + col
#pragma unroll
    for (int m = 0; m < 2; ++m)
#pragma unroll
        for (int nt = 0; nt < 8; ++nt)
#pragma unroll
            for (int r = 0; r < 4; ++r)
                epil[wv][m * 16 + quad * 4 + r][nt * 16 + col] =
                    acc[m][nt][r] + accc[m][nt][r] * INV_SPLIT_SCALE;
    __syncthreads();

    // ---- reduce K-quarters + top-8 + renorm softmax: 8 tokens per wave ----
    for (int i = 0; i < 8; ++i) {
        const int t = wv * 8 + i;
        float v0 = 0.f, v1 = 0.f;
#pragma unroll
        for (int q = 0; q < KSPLIT; ++q) {
            float2 p = *(const float2*)(&epil[q][t][2 * lane]);
            v0 += p.x; v1 += p.y;
        }
        const int i0 = 2 * lane, i1 = 2 * lane + 1;

        float topv[TOPK];
        int topi[TOPK];
#pragma unroll
        for (int s = 0; s < TOPK; ++s) {
            float mv = (v0 >= v1) ? v0 : v1;          // tie -> smaller index
            int   mi = (v0 >= v1) ? i0 : i1;
#pragma unroll
            for (int off = 32; off >= 1; off >>= 1) { // wave butterfly argmax (verified R1/R3)
                float ov = __shfl_xor(mv, off);
                int   oi = __shfl_xor(mi, off);
                if (ov > mv || (ov == mv && oi < mi)) { mv = ov; mi = oi; }
            }
            topv[s] = mv; topi[s] = mi;
            if (i0 == mi) v0 = -INFINITY;
            if (i1 == mi) v1 = -INFINITY;
        }

        const float m = topv[0];
        float sum = 0.f;
#pragma unroll
        for (int s = 0; s < TOPK; ++s) sum += expf(topv[s] - m);
        const float inv = 1.f / sum;

        float myv = topv[0]; int myi = topi[0];
#pragma unroll
        for (int s = 1; s < TOPK; ++s)
            if (lane == s) { myv = topv[s]; myi = topi[s]; }

        if (lane < TOPK) {
            long tok = tok0 + t;
            out_idx[tok * TOPK + lane] = (float)myi;
            out_w[tok * TOPK + lane]   = expf(myv - m) * inv;
        }
    }
}

extern "C" void kernel_launch(void* const* d_in, const int* in_sizes, int n_in,
                              void* d_out, int out_size, void* d_ws, size_t ws_size,
                              hipStream_t stream) {
    const float* x = (const float*)d_in[0];   // [4,4096,2048] fp32
    const float* w = (const float*)d_in[1];   // [128,2048] fp32 (K-major)
    float* out = (float*)d_out;               // [T*8 idx][T*8 weights] flat fp32

    unsigned short* w1 = (unsigned short*)d_ws;            // 512 KB
    unsigned short* w2 = w1 + (size_t)NEXP * HDIM;         // 512 KB

    split_w<<<(NEXP * HDIM) / 256, 256, 0, stream>>>(w, w1, w2);
    moe_gate<<<T_TOKENS / 32, 256, 0, stream>>>(x, w1, w2, out, out + (size_t)T_TOKENS * TOPK);
}

// Round 5
// 264.800 us; speedup vs baseline: 1.2076x; 1.0590x over previous
//
#include <hip/hip_runtime.h>
#include <math.h>

#define T_TOKENS 16384
#define HDIM     2048
#define NEXP     128
#define TOPK     8

#define BK    64                 // k per chunk (2 MFMA k-steps)
#define NCH   (HDIM / BK)        // 32 chunks
#define KPAD  72                 // LDS x-row stride in f16: uniform bank spread, 16B aligned

#define F16_MIN_NORM    6.1035156e-05f
#define SPLIT_SCALE     4096.0f
#define INV_SPLIT_SCALE 2.44140625e-04f   // 2^-12

typedef __attribute__((ext_vector_type(8))) _Float16 f16x8;  // A/B frag: 8 f16 = 4 VGPR
typedef __attribute__((ext_vector_type(4))) float    f32x4;  // C/D frag

// x = hi + lo*2^-12 (f16 RNE each); residual <= 2^-24|x|. Numerics verified (R3/R4 PASS).
__device__ __forceinline__ void f16split(float f, _Float16& hi, _Float16& lo) {
    _Float16 h = (_Float16)f;
    float back = (float)h;
    if (fabsf(f) < F16_MIN_NORM) { h = (_Float16)0.f; back = 0.f; }
    lo = (_Float16)((f - back) * SPLIT_SCALE);
    hi = h;
}

// ---- prep: split w AND repack into MFMA B-frag order ----
// packed[s] layout: ((kk*8 + nt)*64 + lane) * 8 f16, kk = 32-k step (0..63), nt = expert/16.
// Gate's B load = one dwordx4 at +lane*16B: fully coalesced 1 KB burst.
__global__ __launch_bounds__(256) void pack_w(const float* __restrict__ w,
                                              unsigned short* __restrict__ wp1,
                                              unsigned short* __restrict__ wp2) {
    int p = blockIdx.x * 256 + threadIdx.x;       // 0 .. 64*8*64-1
    int lane = p & 63, nt = (p >> 6) & 7, kk = p >> 9;
    int col = lane & 15, quad = lane >> 4;
    const float* src = w + (size_t)(nt * 16 + col) * HDIM + kk * 32 + quad * 8;
    unsigned short h[8], l[8];
#pragma unroll
    for (int j = 0; j < 8; ++j) {
        _Float16 hh, ll;
        f16split(src[j], hh, ll);
        union { _Float16 x; unsigned short u; } ch, cl;
        ch.x = hh; cl.x = ll;
        h[j] = ch.u; l[j] = cl.u;
    }
    *(uint4*)(wp1 + (size_t)p * 8) = *(const uint4*)h;   // coalesced 16B stores
    *(uint4*)(wp2 + (size_t)p * 8) = *(const uint4*)l;
}

// ---- fused gate: LDS-staged A (double-buffered, 1 barrier/chunk), frag-packed B from L2 ----
// Block = 256 thr = 4 waves, 32 tokens x 128 experts; wave wv owns experts [wv*32, +32)
// (n-tiles 2wv, 2wv+1) for ALL 32 tokens (m-tiles 0,1) over full K.
__global__ __launch_bounds__(256, 2) void moe_gate(const float* __restrict__ x,
                                                   const unsigned short* __restrict__ wp1,
                                                   const unsigned short* __restrict__ wp2,
                                                   float* __restrict__ out_idx,
                                                   float* __restrict__ out_w) {
    // staging: 2 buffers x {x1,x2} planes of [32][KPAD] f16 (4608 B each) = 18432 B
    __shared__ __align__(16) unsigned char smem[18432];
    unsigned short* xbuf[2][2];
    xbuf[0][0] = (unsigned short*)smem;
    xbuf[0][1] = (unsigned short*)(smem + 4608);
    xbuf[1][0] = (unsigned short*)(smem + 9216);
    xbuf[1][1] = (unsigned short*)(smem + 13824);
    float* epil = (float*)smem;                    // epilogue union: [32][132] f32 = 16896 B

    const int tid  = threadIdx.x;
    const int lane = tid & 63;
    const int wv   = tid >> 6;
    const int col  = lane & 15;       // A: m, B: n, D: col
    const int quad = lane >> 4;       // A/B: k-segment, D: row group
    const long tok0 = (long)blockIdx.x * 32;

    // staging source: thread f -> x[tok0 + (f>>3)][ch*64 + (f&7)*8 .. +8] (32 B contiguous,
    // consecutive threads contiguous within a row -> coalesced)
    const int srow = tid >> 3, scol = (tid & 7) * 8;
    const float* xg = x + (tok0 + srow) * HDIM + scol;
    const int swoff = srow * KPAD + scol;          // f16 index of this thread's LDS slot

    f32x4 acc[2][2], accc[2][2];                   // [m][n] main + cross
#pragma unroll
    for (int m = 0; m < 2; ++m)
#pragma unroll
        for (int n = 0; n < 2; ++n) { acc[m][n] = (f32x4){0,0,0,0}; accc[m][n] = (f32x4){0,0,0,0}; }

    float4 xv0, xv1;                               // prefetched x (8 floats)

    auto cvt_store = [&](int buf) {
        const float f[8] = {xv0.x, xv0.y, xv0.z, xv0.w, xv1.x, xv1.y, xv1.z, xv1.w};
        unsigned short h[8], l[8];
#pragma unroll
        for (int j = 0; j < 8; ++j) {
            _Float16 hh, ll;
            f16split(f[j], hh, ll);
            union { _Float16 x; unsigned short u; } ch, cl;
            ch.x = hh; cl.x = ll;
            h[j] = ch.u; l[j] = cl.u;
        }
        *(uint4*)(xbuf[buf][0] + swoff) = *(const uint4*)h;
        *(uint4*)(xbuf[buf][1] + swoff) = *(const uint4*)l;
    };

    // prologue: stage chunk 0
    xv0 = *(const float4*)(xg);
    xv1 = *(const float4*)(xg + 4);
    cvt_store(0);
    __syncthreads();

    for (int ch = 0; ch < NCH; ++ch) {
        const int cur = ch & 1;
        // issue next chunk's x loads (coalesced; wait deferred to cvt_store)
        if (ch + 1 < NCH) {
            xv0 = *(const float4*)(xg + (ch + 1) * BK);
            xv1 = *(const float4*)(xg + (ch + 1) * BK + 4);
        }

        // B frags for this chunk: 8 coalesced 1 KB loads from L2-resident packed w
        f16x8 b1[2][2], b2[2][2];                  // [ks][n]
#pragma unroll
        for (int ks = 0; ks < 2; ++ks)
#pragma unroll
            for (int n = 0; n < 2; ++n) {
                const size_t off = ((size_t)((2 * ch + ks) * 8 + (wv * 2 + n)) * 64 + lane) * 8;
                b1[ks][n] = *(const f16x8*)(wp1 + off);
                b2[ks][n] = *(const f16x8*)(wp2 + off);
            }

#pragma unroll
        for (int ks = 0; ks < 2; ++ks) {
            f16x8 a1[2], a2[2];
#pragma unroll
            for (int m = 0; m < 2; ++m) {          // ds_read_b128, uniform 8/bank spread
                const int ao = (m * 16 + col) * KPAD + ks * 32 + quad * 8;
                a1[m] = *(const f16x8*)(xbuf[cur][0] + ao);
                a2[m] = *(const f16x8*)(xbuf[cur][1] + ao);
            }
#pragma unroll
            for (int m = 0; m < 2; ++m)
#pragma unroll
                for (int n = 0; n < 2; ++n) {
                    acc[m][n]  = __builtin_amdgcn_mfma_f32_16x16x32_f16(a1[m], b1[ks][n], acc[m][n],  0, 0, 0);
                    accc[m][n] = __builtin_amdgcn_mfma_f32_16x16x32_f16(a1[m], b2[ks][n], accc[m][n], 0, 0, 0);
                    accc[m][n] = __builtin_amdgcn_mfma_f32_16x16x32_f16(a2[m], b1[ks][n], accc[m][n], 0, 0, 0);
                }
        }

        // stage next chunk into the other buffer (writes don't clash with cur reads)
        if (ch + 1 < NCH) cvt_store(cur ^ 1);
        __syncthreads();
    }

    // ---- epilogue: logits -> LDS [32][132]; D layout: token = m*16+quad*4+r, expert = wv*32+n*16+col
#pragma unroll
    for (int m = 0; m < 2; ++m)
#pragma unroll
        for (int n = 0; n < 2; ++n)
#pragma unroll
            for (int r = 0; r < 4; ++r)
                epil[(m * 16 + quad * 4 + r) * 132 + wv * 32 + n * 16 + col] =
                    acc[m][n][r] + accc[m][n][r] * INV_SPLIT_SCALE;
    __syncthreads();

    // ---- top-8 + renorm softmax: 8 tokens per wave (butterfly verified R1/R3/R4) ----
    for (int i = 0; i < 8; ++i) {
        const int t = wv * 8 + i;
        float2 p = *(const float2*)(epil + t * 132 + 2 * lane);
        float v0 = p.x, v1 = p.y;
        const int i0 = 2 * lane, i1 = 2 * lane + 1;

        float topv[TOPK];
        int topi[TOPK];
#pragma unroll
        for (int s = 0; s < TOPK; ++s) {
            float mv = (v0 >= v1) ? v0 : v1;          // tie -> smaller index
            int   mi = (v0 >= v1) ? i0 : i1;
#pragma unroll
            for (int off = 32; off >= 1; off >>= 1) {
                float ov = __shfl_xor(mv, off);
                int   oi = __shfl_xor(mi, off);
                if (ov > mv || (ov == mv && oi < mi)) { mv = ov; mi = oi; }
            }
            topv[s] = mv; topi[s] = mi;
            if (i0 == mi) v0 = -INFINITY;
            if (i1 == mi) v1 = -INFINITY;
        }

        const float m = topv[0];
        float sum = 0.f;
#pragma unroll
        for (int s = 0; s < TOPK; ++s) sum += expf(topv[s] - m);
        const float inv = 1.f / sum;

        float myv = topv[0]; int myi = topi[0];
#pragma unroll
        for (int s = 1; s < TOPK; ++s)
            if (lane == s) { myv = topv[s]; myi = topi[s]; }

        if (lane < TOPK) {
            long tok = tok0 + t;
            out_idx[tok * TOPK + lane] = (float)myi;
            out_w[tok * TOPK + lane]   = expf(myv - m) * inv;
        }
    }
}

extern "C" void kernel_launch(void* const* d_in, const int* in_sizes, int n_in,
                              void* d_out, int out_size, void* d_ws, size_t ws_size,
                              hipStream_t stream) {
    const float* x = (const float*)d_in[0];   // [4,4096,2048] fp32
    const float* w = (const float*)d_in[1];   // [128,2048] fp32
    float* out = (float*)d_out;               // [T*8 idx][T*8 weights] flat fp32

    unsigned short* wp1 = (unsigned short*)d_ws;           // 512 KB packed hi
    unsigned short* wp2 = wp1 + (size_t)NEXP * HDIM;       // 512 KB packed lo

    pack_w<<<(64 * 8 * 64) / 256, 256, 0, stream>>>(w, wp1, wp2);
    moe_gate<<<T_TOKENS / 32, 256, 0, stream>>>(x, wp1, wp2, out, out + (size_t)T_TOKENS * TOPK);
}

// Round 6
// 254.605 us; speedup vs baseline: 1.2559x; 1.0400x over previous
//
#include <hip/hip_runtime.h>
#include <math.h>

#define T_TOKENS 16384
#define HDIM     2048
#define NEXP     128
#define TOPK     8

#define KSPLIT   4
#define KRANGE   (HDIM / KSPLIT)   // 512 k per wave
#define BK       64                // k per staged chunk (2 MFMA k-steps)
#define NCHW     (KRANGE / BK)     // 8 chunks per wave
#define KPAD     72                // f16 row stride in staging LDS (144 B)

#define F16_MIN_NORM    6.1035156e-05f
#define SPLIT_SCALE     4096.0f
#define INV_SPLIT_SCALE 2.44140625e-04f   // 2^-12

typedef __attribute__((ext_vector_type(8))) _Float16 f16x8;  // A/B frag: 4 VGPR
typedef __attribute__((ext_vector_type(4))) float    f32x4;  // C/D frag
typedef __attribute__((ext_vector_type(4))) float    f32x4v; // for nontemporal loads

// x = hi + lo*2^-12 (f16 RNE each); residual <= 2^-24|x|. Numerics verified R3/R4/R5.
__device__ __forceinline__ void f16split(float f, _Float16& hi, _Float16& lo) {
    _Float16 h = (_Float16)f;
    float back = (float)h;
    if (fabsf(f) < F16_MIN_NORM) { h = (_Float16)0.f; back = 0.f; }
    lo = (_Float16)((f - back) * SPLIT_SCALE);
    hi = h;
}

// ---- prep: split w AND repack into MFMA B-frag order (verified R5) ----
// packed[s]: ((kk*8 + nt)*64 + lane) * 8 f16; kk = global 32-k step, nt = expert/16.
__global__ __launch_bounds__(256) void pack_w(const float* __restrict__ w,
                                              unsigned short* __restrict__ wp1,
                                              unsigned short* __restrict__ wp2) {
    int p = blockIdx.x * 256 + threadIdx.x;       // 0 .. 64*8*64-1
    int lane = p & 63, nt = (p >> 6) & 7, kk = p >> 9;
    int col = lane & 15, quad = lane >> 4;
    const float* src = w + (size_t)(nt * 16 + col) * HDIM + kk * 32 + quad * 8;
    unsigned short h[8], l[8];
#pragma unroll
    for (int j = 0; j < 8; ++j) {
        _Float16 hh, ll;
        f16split(src[j], hh, ll);
        union { _Float16 x; unsigned short u; } ch, cl;
        ch.x = hh; cl.x = ll;
        h[j] = ch.u; l[j] = cl.u;
    }
    *(uint4*)(wp1 + (size_t)p * 8) = *(const uint4*)h;
    *(uint4*)(wp2 + (size_t)p * 8) = *(const uint4*)l;
}

// ---- fused gate: K-split x4, wave-private staging, no K-loop barriers ----
// Block = 256 thr = 4 waves; block owns 16 tokens x 128 experts; wave wv owns
// K-quarter [wv*512,+512), all 8 n-tiles. Grid = T/16 = 1024 -> 4 blocks/CU, 16 waves/CU.
__global__ __launch_bounds__(256, 4) void moe_gate(const float* __restrict__ x,
                                                   const unsigned short* __restrict__ wp1,
                                                   const unsigned short* __restrict__ wp2,
                                                   float* __restrict__ out_idx,
                                                   float* __restrict__ out_w) {
    // union: staging 4 waves x 2 planes x [16][KPAD] f16 (4608 B/wave) = 18432 B
    //        epilogue [KSPLIT][16][132] f32 = 33792 B
    __shared__ __align__(16) unsigned char smem[33792];
    float* epil = (float*)smem;

    const int tid  = threadIdx.x;
    const int lane = tid & 63;
    const int wv   = tid >> 6;
    const int col  = lane & 15;       // A: m, B: n, D: col
    const int quad = lane >> 4;       // A/B: k-seg, D: row group
    const long tok0 = (long)blockIdx.x * 16;
    const int kbase = wv * KRANGE;

    unsigned short* buf0 = (unsigned short*)(smem + wv * 4608);          // x-hi plane
    unsigned short* buf1 = (unsigned short*)(smem + wv * 4608 + 2304);   // x-lo plane

    // staging source: lane -> row = lane>>2 (16 rows), 64 B segment seg = lane&3
    const int srow = lane >> 2, scol = (lane & 3) * 16;
    const float* xg = x + (tok0 + srow) * HDIM + kbase + scol;
    const int woff = srow * KPAD + scol;           // f16 idx of this lane's LDS slot

    f32x4 acc[8], accc[8];                         // main + cross per n-tile
#pragma unroll
    for (int n = 0; n < 8; ++n) { acc[n] = (f32x4){0,0,0,0}; accc[n] = (f32x4){0,0,0,0}; }

    for (int ch = 0; ch < NCHW; ++ch) {
        // 1) load this chunk's 16 f32 (nontemporal: keep packed-w L2-resident)
        f32x4v xv[4];
#pragma unroll
        for (int j = 0; j < 4; ++j)
            xv[j] = __builtin_nontemporal_load((const f32x4v*)(xg + ch * BK + 4 * j));

        // 2) split + pack -> wave-private LDS
        unsigned short h[16], l[16];
#pragma unroll
        for (int j = 0; j < 16; ++j) {
            _Float16 hh, ll;
            f16split(xv[j >> 2][j & 3], hh, ll);
            union { _Float16 x; unsigned short u; } ch_, cl_;
            ch_.x = hh; cl_.x = ll;
            h[j] = ch_.u; l[j] = cl_.u;
        }
        *(uint4*)(buf0 + woff)     = *(const uint4*)(h);
        *(uint4*)(buf0 + woff + 8) = *(const uint4*)(h + 8);
        *(uint4*)(buf1 + woff)     = *(const uint4*)(l);
        *(uint4*)(buf1 + woff + 8) = *(const uint4*)(l + 8);
        __builtin_amdgcn_wave_barrier();           // LDS RAW fence (intra-wave, no instr)

        // 3) consume: 2 k-steps x 8 n-tiles x 3 MFMA
#pragma unroll
        for (int ks = 0; ks < 2; ++ks) {
            const int kk = wv * 16 + ch * 2 + ks;  // global 32-k step for B
            f16x8 a1 = *(const f16x8*)(buf0 + col * KPAD + ks * 32 + quad * 8);
            f16x8 a2 = *(const f16x8*)(buf1 + col * KPAD + ks * 32 + quad * 8);
#pragma unroll
            for (int nt = 0; nt < 8; ++nt) {
                const size_t off = ((size_t)(kk * 8 + nt) * 64 + lane) * 8;
                f16x8 b1 = *(const f16x8*)(wp1 + off);
                f16x8 b2 = *(const f16x8*)(wp2 + off);
                acc[nt]  = __builtin_amdgcn_mfma_f32_16x16x32_f16(a1, b1, acc[nt],  0, 0, 0);
                accc[nt] = __builtin_amdgcn_mfma_f32_16x16x32_f16(a1, b2, accc[nt], 0, 0, 0);
                accc[nt] = __builtin_amdgcn_mfma_f32_16x16x32_f16(a2, b1, accc[nt], 0, 0, 0);
            }
        }
        __builtin_amdgcn_wave_barrier();           // WAR fence before next chunk's writes
    }

    __syncthreads();   // staging slices about to be overwritten by epilogue partials

    // ---- epilogue: partials -> LDS; D layout: token = quad*4+r, expert = nt*16+col ----
#pragma unroll
    for (int nt = 0; nt < 8; ++nt)
#pragma unroll
        for (int r = 0; r < 4; ++r)
            epil[(wv * 16 + quad * 4 + r) * 132 + nt * 16 + col] =
                acc[nt][r] + accc[nt][r] * INV_SPLIT_SCALE;
    __syncthreads();

    // ---- reduce K-quarters + top-8 + renorm softmax: 4 tokens per wave ----
    for (int i = 0; i < 4; ++i) {
        const int t = wv * 4 + i;
        float v0 = 0.f, v1 = 0.f;
#pragma unroll
        for (int q = 0; q < KSPLIT; ++q) {
            float2 p = *(const float2*)(epil + (q * 16 + t) * 132 + 2 * lane);
            v0 += p.x; v1 += p.y;
        }
        const int i0 = 2 * lane, i1 = 2 * lane + 1;

        float topv[TOPK];
        int topi[TOPK];
#pragma unroll
        for (int s = 0; s < TOPK; ++s) {
            float mv = (v0 >= v1) ? v0 : v1;          // tie -> smaller index
            int   mi = (v0 >= v1) ? i0 : i1;
#pragma unroll
            for (int off = 32; off >= 1; off >>= 1) { // butterfly argmax (verified R1-R5)
                float ov = __shfl_xor(mv, off);
                int   oi = __shfl_xor(mi, off);
                if (ov > mv || (ov == mv && oi < mi)) { mv = ov; mi = oi; }
            }
            topv[s] = mv; topi[s] = mi;
            if (i0 == mi) v0 = -INFINITY;
            if (i1 == mi) v1 = -INFINITY;
        }

        const float m = topv[0];
        float sum = 0.f;
#pragma unroll
        for (int s = 0; s < TOPK; ++s) sum += expf(topv[s] - m);
        const float inv = 1.f / sum;

        float myv = topv[0]; int myi = topi[0];
#pragma unroll
        for (int s = 1; s < TOPK; ++s)
            if (lane == s) { myv = topv[s]; myi = topi[s]; }

        if (lane < TOPK) {
            long tok = tok0 + t;
            out_idx[tok * TOPK + lane] = (float)myi;
            out_w[tok * TOPK + lane]   = expf(myv - m) * inv;
        }
    }
}

extern "C" void kernel_launch(void* const* d_in, const int* in_sizes, int n_in,
                              void* d_out, int out_size, void* d_ws, size_t ws_size,
                              hipStream_t stream) {
    const float* x = (const float*)d_in[0];   // [4,4096,2048] fp32
    const float* w = (const float*)d_in[1];   // [128,2048] fp32
    float* out = (float*)d_out;               // [T*8 idx][T*8 weights] flat fp32

    unsigned short* wp1 = (unsigned short*)d_ws;           // 512 KB packed hi
    unsigned short* wp2 = wp1 + (size_t)NEXP * HDIM;       // 512 KB packed lo

    pack_w<<<(64 * 8 * 64) / 256, 256, 0, stream>>>(w, wp1, wp2);
    moe_gate<<<T_TOKENS / 16, 256, 0, stream>>>(x, wp1, wp2, out, out + (size_t)T_TOKENS * TOPK);
}